// Round 22
// baseline (83.199 us; speedup 1.0000x reference)
//
#include <hip/hip_runtime.h>

#define BB 8
#define NN 2048
#define HH 4
#define EE 64
#define MAXJ 128
#define NEG 0.2f

// ws float offsets
static constexpr int OFF_WGW  = 0;                       // [4][64] = 0.25*WgWst (L1 block 0 writes)
static constexpr int OFF_S    = 256;                     // [8]
static constexpr int OFF_SWS  = 288;                     // [N][64]
static constexpr int OFF_SATT = OFF_SWS + NN * EE;       // [N][32]  (g = b*4+h)
static constexpr int OFF_PART = OFF_SATT + NN * 32;      // [8][N][64] relu partials (~4MB)

// ---- L1: per-row everything: wgw/cs/ct + scan + sws + softmax + relu-partials ----
__global__ __launch_bounds__(256) void k_row(const int* __restrict__ adj,
                                             const float* __restrict__ state,
                                             const float* __restrict__ strucEmb,
                                             const float* __restrict__ Ws,
                                             const float* __restrict__ W_gat,
                                             const float* __restrict__ att,
                                             const float* __restrict__ Wst,
                                             float* __restrict__ ws) {
    __shared__ float s_T[EE * 65];       // WstT, then re-staged as WsT
    __shared__ float s_wgw[HH * EE];     // 0.25 * WgWst[h][f]
    __shared__ float s_cs[HH], s_ct[HH];
    __shared__ int   s_jl[MAXJ];
    __shared__ int   s_cnt;
    __shared__ float s_y[BB * MAXJ];
    __shared__ float s_satt[32];
    __shared__ float s_sws[EE];
    const int i = blockIdx.x;
    const int t = threadIdx.x;
    const int w = t >> 6, lane = t & 63;

    // P0: stage Wst transposed: s_T[e*65+f] = Wst[f][e]
    for (int q = 0; q < 16; ++q) {
        int it = w * 16 + q;
        s_T[lane * 65 + it] = Wst[it * EE + lane];
    }
    __syncthreads();

    // P1: wgw[h=w][f=lane] (0.25-folded); cs/ct by 8 lanes
    {
        float acc = 0.f;
        const float* wgh = W_gat + w * EE;
        for (int e = 0; e < EE; ++e) acc += wgh[e] * s_T[e * 65 + lane];
        s_wgw[t] = 0.25f * acc;
        if (t < 2 * HH) {
            int h = t & 3;
            const float* wgx = W_gat + h * EE;
            const float* av  = att + h * 2 * EE + (t >= HH ? EE : 0);
            float a2 = 0.f;
            for (int e = 0; e < EE; ++e) a2 += wgx[e] * av[e];
            if (t < HH) s_cs[h] = a2; else s_ct[h] = a2;
        }
    }
    __syncthreads();

    // P2: wave0 scans adj row i (int32, verified r11/r13); waves1-3 restage s_T = WsT
    if (w == 0) {
        const int* a = adj + (size_t)i * NN;
        int cnt = 0;
        for (int it = 0; it < NN / 64; ++it) {
            int j = it * 64 + lane;
            bool edge = (a[j] == 0);
            unsigned long long m = __ballot(edge);
            if (edge) {
                int pos = cnt + __popcll(m & ((1ull << lane) - 1ull));
                if (pos < MAXJ) s_jl[pos] = j;
            }
            cnt += __popcll(m);
        }
        if (lane == 0) s_cnt = cnt > MAXJ ? MAXJ : cnt;
    } else {
        for (int it = w - 1; it < EE; it += 3)
            s_T[lane * 65 + it] = Ws[it * EE + lane];   // s_T[e*65+f] = Ws[f][e]
    }
    __syncthreads();
    const int cnt = s_cnt;

    // P3: wave0 computes sws; waves1-3 stage neighbor state values
    if (w == 0) {
        float v = strucEmb[(size_t)i * EE + lane];
        float acc = 0.f;
        for (int e = 0; e < EE; ++e) acc += __shfl(v, e) * s_T[e * 65 + lane];
        s_sws[lane] = acc;
        ws[OFF_SWS + i * EE + lane] = acc;
    } else {
        for (int x = t - 64; x < BB * MAXJ; x += 192) {
            int k = x & (MAXJ - 1);
            if (k < cnt) s_y[x] = state[(x >> 7) * NN + s_jl[k]];
        }
    }
    __syncthreads();

    // P4: softmax, 32 groups x 8 lanes = (b,h)
    {
        int g = t >> 3, k0 = t & 7, b = g >> 2, h = g & 3;
        const float* yb = s_y + b * MAXJ;
        float ct = s_ct[h];
        float si = state[b * NN + i] * s_cs[h];
        float mmax = -1e30f;
        for (int k = k0; k < cnt; k += 8) {
            float e = si + ct * yb[k]; e = e > 0.f ? e : NEG * e;
            mmax = fmaxf(mmax, e);
        }
        for (int o = 4; o; o >>= 1) mmax = fmaxf(mmax, __shfl_xor(mmax, o, 8));
        float den = 0.f, num = 0.f;
        for (int k = k0; k < cnt; k += 8) {
            float y = yb[k];
            float e = si + ct * y; e = e > 0.f ? e : NEG * e;
            float p = expf(e - mmax);
            den += p; num += p * y;
        }
        for (int o = 4; o; o >>= 1) { den += __shfl_xor(den, o, 8); num += __shfl_xor(num, o, 8); }
        if (k0 == 0) {
            float sv = num / den;
            s_satt[g] = sv;
            ws[OFF_SATT + i * 32 + g] = sv;
        }
    }
    __syncthreads();

    // P5: relu partials: PART[b][i][f]
    for (int q = 0; q < 2; ++q) {
        int idx = q * 256 + t, b = idx >> 6, f = idx & 63;
        float x = s_sws[f];
        for (int h = 0; h < HH; ++h)
            x += s_satt[b * 4 + h] * s_wgw[h * EE + f];
        ws[OFF_PART + ((size_t)b * NN + i) * EE + f] = fmaxf(x, 0.f);
    }
    if (i == 0) ws[OFF_WGW + t] = s_wgw[t];   // publish for L3 (0.25-folded)
}

// ---- L2: S[b] = relu(se @ l1w.T + l1b) . l3w[:64] + l3b ----
__global__ __launch_bounds__(1024) void k_S2(const float* __restrict__ lin1_w,
                                             const float* __restrict__ lin1_b,
                                             const float* __restrict__ lin3_w,
                                             const float* __restrict__ lin3_b,
                                             float* __restrict__ ws) {
    __shared__ float s_red[1024];
    __shared__ float s_l1T[EE * 65];
    __shared__ float s_se[EE];
    const int b = blockIdx.x;
    const int t = threadIdx.x;
    const int sl = t >> 6, f = t & 63;
    // stage l1T (coalesced read, padded write)
    for (int k = t; k < EE * EE; k += 1024) {
        int o = k >> 6, f2 = k & 63;
        s_l1T[f2 * 65 + o] = lin1_w[k];
    }
    // streaming reduction over this b's contiguous partials
    float acc = 0.f;
    const float* p = ws + OFF_PART + (size_t)b * NN * EE;
    for (int i = sl; i < NN; i += 16)
        acc += p[i * EE + f];
    s_red[t] = acc;
    __syncthreads();
    if (t < EE) {
        float se = 0.f;
        for (int s = 0; s < 16; ++s) se += s_red[s * 64 + t];
        s_se[t] = se;
    }
    __syncthreads();
    if (t < EE) {
        float bs = lin1_b[t];
        for (int f2 = 0; f2 < EE; ++f2) bs += s_se[f2] * s_l1T[f2 * 65 + t];
        float r = fmaxf(bs, 0.f) * lin3_w[t];
        for (int o = 32; o; o >>= 1) r += __shfl_xor(r, o);
        if (t == 0) ws[OFF_S + b] = r + lin3_b[0];
    }
}

// ---- L3: out[b,i]; 4 rows per block, l2T staged once per block ----
__global__ __launch_bounds__(256) void k_out2(const float* __restrict__ lin2_w,
                                              const float* __restrict__ lin2_b,
                                              const float* __restrict__ lin3_w,
                                              const float* __restrict__ ws,
                                              float* __restrict__ out) {
    __shared__ float s_l2T[EE * 65];
    __shared__ float s_wgw[HH * EE];
    __shared__ float s_S[BB];
    __shared__ float s_l2b[EE], s_l3[EE];
    const int t = threadIdx.x;
    const int w = t >> 6, lane = t & 63;
    for (int k = t; k < EE * EE; k += 256) {
        int fp = k >> 6, f = k & 63;
        s_l2T[f * 65 + fp] = lin2_w[k];
    }
    s_wgw[t] = ws[OFF_WGW + t];               // 0.25-folded
    if (t < BB) s_S[t] = ws[OFF_S + t];
    if (t < EE) { s_l2b[t] = lin2_b[t]; s_l3[t] = lin3_w[EE + t]; }
    __syncthreads();

    const int i = blockIdx.x * 4 + w;
    float xsws = ws[OFF_SWS + i * EE + lane];
    float sa = (lane < 32) ? ws[OFF_SATT + i * 32 + lane] : 0.f;
    for (int b = 0; b < BB; ++b) {
        float xv = xsws;
        for (int h = 0; h < HH; ++h)
            xv += __shfl(sa, b * 4 + h) * s_wgw[h * EE + lane];
        xv = fmaxf(xv, 0.f);
        float acc = s_l2b[lane];
        for (int f = 0; f < EE; ++f) acc += __shfl(xv, f) * s_l2T[f * 65 + lane];
        float r = fmaxf(acc, 0.f) * s_l3[lane];
        for (int o = 32; o; o >>= 1) r += __shfl_xor(r, o);
        if (lane == 0) out[(size_t)b * NN + i] = s_S[b] + r;
    }
}

extern "C" void kernel_launch(void* const* d_in, const int* in_sizes, int n_in,
                              void* d_out, int out_size, void* d_ws, size_t ws_size,
                              hipStream_t stream) {
    const float* state    = (const float*)d_in[0];
    const float* strucEmb = (const float*)d_in[1];
    const int*   adj      = (const int*)d_in[2];   // int32 {0,1}, verified r11/r13
    const float* W_gat    = (const float*)d_in[3];
    const float* att      = (const float*)d_in[4];
    const float* Ws       = (const float*)d_in[5];
    const float* Wst      = (const float*)d_in[6];
    const float* lin1_w   = (const float*)d_in[7];
    const float* lin1_b   = (const float*)d_in[8];
    const float* lin2_w   = (const float*)d_in[9];
    const float* lin2_b   = (const float*)d_in[10];
    const float* lin3_w   = (const float*)d_in[11];
    const float* lin3_b   = (const float*)d_in[12];
    float* ws = (float*)d_ws;
    float* out = (float*)d_out;   // f32 output, verified r13

    k_row <<<dim3(NN),     dim3(256),  0, stream>>>(adj, state, strucEmb, Ws, W_gat, att, Wst, ws);
    k_S2  <<<dim3(BB),     dim3(1024), 0, stream>>>(lin1_w, lin1_b, lin3_w, lin3_b, ws);
    k_out2<<<dim3(NN / 4), dim3(256),  0, stream>>>(lin2_w, lin2_b, lin3_w, ws, out);
}

// Round 23
// 52.108 us; speedup vs baseline: 1.5967x; 1.5967x over previous
//
#include <hip/hip_runtime.h>

#define BB 8
#define NN 2048
#define HH 4
#define EE 64
#define MAXJ 128
#define NEG 0.2f
#define NCHUNK 32

static constexpr int OFF_CSRC  = 0;                          // [4]
static constexpr int OFF_CTGT  = 4;                          // [4]
static constexpr int OFF_WGWST = 8;                          // [4][64] (unfolded)
static constexpr int OFF_S     = 264;                        // [8]
static constexpr int OFF_SWS   = 288;                        // [N][64]
static constexpr int OFF_SATT  = OFF_SWS + NN * EE;          // [N][32]  (g = b*4+h)
static constexpr int OFF_PART  = OFF_SATT + NN * 32;         // [NCHUNK*B][64]

// ---- prep: c_src/c_tgt + WgWst[h][f] ----
__global__ __launch_bounds__(256) void k_prep(const float* __restrict__ W_gat,
                                              const float* __restrict__ att,
                                              const float* __restrict__ Wst,
                                              float* __restrict__ ws) {
    __shared__ float wg[HH * EE];
    int t = threadIdx.x; // 256
    wg[t] = W_gat[t];
    __syncthreads();
    if (t < HH) {
        float cs = 0.f, ct = 0.f;
        for (int e = 0; e < EE; ++e) {
            cs += wg[t * EE + e] * att[t * 2 * EE + e];
            ct += wg[t * EE + e] * att[t * 2 * EE + EE + e];
        }
        ws[OFF_CSRC + t] = cs;
        ws[OFF_CTGT + t] = ct;
    }
    int h = t >> 6, f = t & 63;
    float acc = 0.f;
    for (int e = 0; e < EE; ++e) acc += wg[h * EE + e] * Wst[f * EE + e];
    ws[OFF_WGWST + t] = acc; // WgWst[h][f]
}

// ---- fused per-row: adj scan + SWS row (LDS-transposed Ws) + sparse softmax ----
__global__ __launch_bounds__(256) void k_fsatt(const int* __restrict__ adj,
                                               const float* __restrict__ state,
                                               const float* __restrict__ strucEmb,
                                               const float* __restrict__ Ws,
                                               float* __restrict__ ws) {
    __shared__ float s_wsT[EE * 65];   // s_wsT[e*65+f] = Ws[f][e]
    __shared__ int   s_jl[MAXJ];
    __shared__ int   s_cnt;
    __shared__ float s_y[BB * MAXJ];
    const int i = blockIdx.x;
    const int t = threadIdx.x;
    const int w = t >> 6, lane = t & 63;

    if (w == 0) {
        // wave 0: deterministic neighbor-list compaction of row i (adj int32, r11/r13)
        const int* a = adj + (size_t)i * NN;
        int cnt = 0;
        for (int it = 0; it < NN / 64; ++it) {
            int j = it * 64 + lane;
            bool edge = (a[j] == 0);
            unsigned long long m = __ballot(edge);
            if (edge) {
                int pos = cnt + __popcll(m & ((1ull << lane) - 1ull));
                if (pos < MAXJ) s_jl[pos] = j;
            }
            cnt += __popcll(m);
        }
        if (lane == 0) s_cnt = cnt > MAXJ ? MAXJ : cnt;
    } else if (w == 1) {
        // wave 1 (concurrent): stage Ws transposed, coalesced reads
        for (int it = 0; it < EE; ++it)
            s_wsT[lane * 65 + it] = Ws[it * EE + lane];
    }
    __syncthreads();
    const int cnt = s_cnt;

    if (w == 0) {
        // SWS[i][f=lane] from LDS
        float v = strucEmb[(size_t)i * EE + lane];
        float acc = 0.f;
        for (int e = 0; e < EE; ++e)
            acc += __shfl(v, e) * s_wsT[e * 65 + lane];
        ws[OFF_SWS + i * EE + lane] = acc;
    } else {
        // waves 1-3: stage neighbor state values for all 8 batches
        for (int x = t - 64; x < BB * MAXJ; x += 192) {
            int k = x & (MAXJ - 1);
            if (k < cnt) s_y[x] = state[(x >> 7) * NN + s_jl[k]];
        }
    }
    __syncthreads();

    // 32 groups x 8 lanes: group = (b,h)
    int g = t >> 3, k0 = t & 7, b = g >> 2, h = g & 3;
    const float* yb = s_y + b * MAXJ;
    float ct = ws[OFF_CTGT + h];
    float si = state[b * NN + i] * ws[OFF_CSRC + h];
    float mmax = -1e30f;
    for (int k = k0; k < cnt; k += 8) {
        float e = si + ct * yb[k]; e = e > 0.f ? e : NEG * e;
        mmax = fmaxf(mmax, e);
    }
    for (int o = 4; o; o >>= 1) mmax = fmaxf(mmax, __shfl_xor(mmax, o, 8));
    float den = 0.f, num = 0.f;
    for (int k = k0; k < cnt; k += 8) {
        float y = yb[k];
        float e = si + ct * y; e = e > 0.f ? e : NEG * e;
        float p = expf(e - mmax);
        den += p; num += p * y;
    }
    for (int o = 4; o; o >>= 1) { den += __shfl_xor(den, o, 8); num += __shfl_xor(num, o, 8); }
    if (k0 == 0) ws[OFF_SATT + i * 32 + g] = num / den;   // [i][32] layout
}

// ---- se partials: block (chunk,b) sums relu(x[b,i,f]) over 64 rows ----
__global__ void k_se(float* __restrict__ ws) {
    int b = blockIdx.x & 7, chunk = blockIdx.x >> 3;
    int t = threadIdx.x; // 256
    int f = t & 63, sl = t >> 6;
    float wgw[HH];
    for (int h = 0; h < HH; ++h) wgw[h] = 0.25f * ws[OFF_WGWST + h * EE + f];
    float acc = 0.f;
    int i0 = chunk * (NN / NCHUNK);
    for (int i = i0 + sl; i < i0 + NN / NCHUNK; i += 4) {
        float v = ws[OFF_SWS + i * EE + f];
        for (int h = 0; h < HH; ++h)
            v += ws[OFF_SATT + i * 32 + b * 4 + h] * wgw[h];   // one line per (b,i)
        acc += fmaxf(v, 0.f);
    }
    __shared__ float red[256];
    red[t] = acc;
    __syncthreads();
    if (t < EE)
        ws[OFF_PART + (size_t)blockIdx.x * EE + t] =
            red[t] + red[t + 64] + red[t + 128] + red[t + 192];
}

// ---- S[b] = relu(se @ l1w.T + l1b) . l3w[:64] + l3b (LDS-transposed l1w) ----
__global__ void k_S(const float* __restrict__ lin1_w, const float* __restrict__ lin1_b,
                    const float* __restrict__ lin3_w, const float* __restrict__ lin3_b,
                    float* __restrict__ ws) {
    int b = blockIdx.x;
    int t = threadIdx.x; // 64
    __shared__ float s_l1T[EE * 65];
    __shared__ float s_se[EE];
    for (int it = 0; it < EE; ++it)
        s_l1T[t * 65 + it] = lin1_w[it * EE + t];
    float se = 0.f;
    for (int c = 0; c < NCHUNK; ++c)
        se += ws[OFF_PART + (size_t)(c * BB + b) * EE + t];
    s_se[t] = se;
    __syncthreads();
    float bs = lin1_b[t];
    for (int f2 = 0; f2 < EE; ++f2) bs += s_se[f2] * s_l1T[f2 * 65 + t];
    float r = fmaxf(bs, 0.f) * lin3_w[t];
    for (int o = 32; o; o >>= 1) r += __shfl_xor(r, o);
    if (t == 0) ws[OFF_S + b] = r + lin3_b[0];
}

// ---- epilogue: 4 rows/block, all 8 batches per row; l2T staged once ----
__global__ __launch_bounds__(256) void k_out2(const float* __restrict__ lin2_w,
                                              const float* __restrict__ lin2_b,
                                              const float* __restrict__ lin3_w,
                                              const float* __restrict__ ws,
                                              float* __restrict__ out) {
    __shared__ float s_l2T[EE * 65];
    __shared__ float s_wgw[HH * EE];   // 0.25-folded
    __shared__ float s_S[BB];
    __shared__ float s_l2b[EE], s_l3[EE];
    const int t = threadIdx.x;
    const int w = t >> 6, lane = t & 63;
    for (int k = t; k < EE * EE; k += 256) {
        int fp = k >> 6, f = k & 63;
        s_l2T[f * 65 + fp] = lin2_w[k];
    }
    s_wgw[t] = 0.25f * ws[OFF_WGWST + t];
    if (t < BB) s_S[t] = ws[OFF_S + t];
    if (t < EE) { s_l2b[t] = lin2_b[t]; s_l3[t] = lin3_w[EE + t]; }
    __syncthreads();

    const int i = blockIdx.x * 4 + w;
    float xsws = ws[OFF_SWS + i * EE + lane];
    float sa = (lane < 32) ? ws[OFF_SATT + i * 32 + lane] : 0.f;   // contiguous
    for (int b = 0; b < BB; ++b) {
        float xv = xsws;
        for (int h = 0; h < HH; ++h)
            xv += __shfl(sa, b * 4 + h) * s_wgw[h * EE + lane];
        xv = fmaxf(xv, 0.f);
        float acc = s_l2b[lane];
        for (int f = 0; f < EE; ++f) acc += __shfl(xv, f) * s_l2T[f * 65 + lane];
        float r = fmaxf(acc, 0.f) * s_l3[lane];
        for (int o = 32; o; o >>= 1) r += __shfl_xor(r, o);
        if (lane == 0) out[(size_t)b * NN + i] = s_S[b] + r;
    }
}

extern "C" void kernel_launch(void* const* d_in, const int* in_sizes, int n_in,
                              void* d_out, int out_size, void* d_ws, size_t ws_size,
                              hipStream_t stream) {
    const float* state    = (const float*)d_in[0];
    const float* strucEmb = (const float*)d_in[1];
    const int*   adj      = (const int*)d_in[2];   // int32 {0,1}, verified r11/r13
    const float* W_gat    = (const float*)d_in[3];
    const float* att      = (const float*)d_in[4];
    const float* Ws       = (const float*)d_in[5];
    const float* Wst      = (const float*)d_in[6];
    const float* lin1_w   = (const float*)d_in[7];
    const float* lin1_b   = (const float*)d_in[8];
    const float* lin2_w   = (const float*)d_in[9];
    const float* lin2_b   = (const float*)d_in[10];
    const float* lin3_w   = (const float*)d_in[11];
    const float* lin3_b   = (const float*)d_in[12];
    float* ws = (float*)d_ws;
    float* out = (float*)d_out;   // f32 output, verified r13

    k_prep <<<dim3(1),           dim3(256), 0, stream>>>(W_gat, att, Wst, ws);
    k_fsatt<<<dim3(NN),          dim3(256), 0, stream>>>(adj, state, strucEmb, Ws, ws);
    k_se   <<<dim3(NCHUNK * BB), dim3(256), 0, stream>>>(ws);
    k_S    <<<dim3(BB),          dim3(64),  0, stream>>>(lin1_w, lin1_b, lin3_w, lin3_b, ws);
    k_out2 <<<dim3(NN / 4),      dim3(256), 0, stream>>>(lin2_w, lin2_b, lin3_w, ws, out);
}

// Round 24
// 48.292 us; speedup vs baseline: 1.7228x; 1.0790x over previous
//
#include <hip/hip_runtime.h>

#define BB 8
#define NN 2048
#define HH 4
#define EE 64
#define MAXJ 128
#define NEG 0.2f
#define NCHUNK 32

static constexpr int OFF_CSRC  = 0;                          // [4]
static constexpr int OFF_CTGT  = 4;                          // [4]
static constexpr int OFF_WGWST = 8;                          // [4][64]
static constexpr int OFF_S     = 264;                        // [8]
static constexpr int OFF_SWS   = 288;                        // [N][64]
static constexpr int OFF_SATT  = OFF_SWS + NN * EE;          // [N][32]
static constexpr int OFF_PART  = OFF_SATT + NN * 32;         // [NCHUNK*B][64]

// ---- sws: 16 rows/block, staged WsT; block 0 also does prep (cs/ct, wgw) ----
__global__ __launch_bounds__(256) void k_sws(const float* __restrict__ strucEmb,
                                             const float* __restrict__ Ws,
                                             const float* __restrict__ W_gat,
                                             const float* __restrict__ att,
                                             const float* __restrict__ Wst,
                                             float* __restrict__ ws) {
    __shared__ float s_wsT[EE * 65];   // s_wsT[e*65+f] = Ws[f][e]
    __shared__ float s_emb[16 * EE];
    const int t = threadIdx.x;
    const int w = t >> 6, lane = t & 63;
    const int i0 = blockIdx.x * 16;
    for (int k = t; k < EE * EE; k += 256)
        s_wsT[(k & 63) * 65 + (k >> 6)] = Ws[k];       // coalesced read
    for (int k = t; k < 16 * EE; k += 256)
        s_emb[k] = strucEmb[(size_t)i0 * EE + k];
    __syncthreads();
    for (int q = 0; q < 4; ++q) {
        int r = w * 4 + q;
        float v = s_emb[r * EE + lane];
        float acc = 0.f;
        for (int e = 0; e < EE; ++e)
            acc += __shfl(v, e) * s_wsT[e * 65 + lane];
        ws[OFF_SWS + (size_t)(i0 + r) * EE + lane] = acc;
    }
    if (blockIdx.x == 0) {
        // prep: wgw[h][f] and cs/ct (one block; reads L2-resident weights)
        int h = t >> 6, f = t & 63;
        float acc = 0.f;
        for (int e = 0; e < EE; ++e) acc += W_gat[h * EE + e] * Wst[f * EE + e];
        ws[OFF_WGWST + t] = acc;
        if (t < 2 * HH) {
            int hh = t & 3;
            const float* wgx = W_gat + hh * EE;
            const float* av  = att + hh * 2 * EE + (t >= HH ? EE : 0);
            float a2 = 0.f;
            for (int e = 0; e < EE; ++e) a2 += wgx[e] * av[e];
            if (t < HH) ws[OFF_CSRC + hh] = a2; else ws[OFF_CTGT + hh] = a2;
        }
    }
}

// ---- fsatt: vectorized 4-wave scan + gather + sparse softmax ----
__global__ __launch_bounds__(256) void k_fsatt(const int* __restrict__ adj,
                                               const float* __restrict__ state,
                                               float* __restrict__ ws) {
    __shared__ int   s_jq[4][MAXJ];
    __shared__ int   s_c[4];
    __shared__ int   s_jl[MAXJ];
    __shared__ int   s_cnt;
    __shared__ float s_y[BB * MAXJ];
    const int i = blockIdx.x;
    const int t = threadIdx.x;
    const int w = t >> 6, lane = t & 63;

    // each wave scans its quarter (512 ints = 128 int4) in 2 iterations
    {
        const int4* a4 = (const int4*)(adj + (size_t)i * NN) + w * 128;
        int base = 0;
        const unsigned long long below = (1ull << lane) - 1ull;
        for (int q = 0; q < 2; ++q) {
            int4 v = a4[q * 64 + lane];
            int j0 = w * 512 + (q * 64 + lane) * 4;
            int eb = (v.x == 0 ? 1 : 0) | (v.y == 0 ? 2 : 0) |
                     (v.z == 0 ? 4 : 0) | (v.w == 0 ? 8 : 0);
            unsigned long long b0 = __ballot(eb & 1), b1 = __ballot(eb & 2);
            unsigned long long b2 = __ballot(eb & 4), b3 = __ballot(eb & 8);
            int pos = base + __popcll(b0 & below) + __popcll(b1 & below)
                           + __popcll(b2 & below) + __popcll(b3 & below);
            if (eb & 1) { if (pos < MAXJ) s_jq[w][pos] = j0 + 0; ++pos; }
            if (eb & 2) { if (pos < MAXJ) s_jq[w][pos] = j0 + 1; ++pos; }
            if (eb & 4) { if (pos < MAXJ) s_jq[w][pos] = j0 + 2; ++pos; }
            if (eb & 8) { if (pos < MAXJ) s_jq[w][pos] = j0 + 3; ++pos; }
            base += __popcll(b0) + __popcll(b1) + __popcll(b2) + __popcll(b3);
        }
        if (lane == 0) s_c[w] = base > MAXJ ? MAXJ : base;
    }
    __syncthreads();
    // deterministic quarter merge (ascending j preserved)
    {
        int start = 0;
        for (int q = 0; q < w; ++q) start += s_c[q];
        int cw = s_c[w];
        for (int k = lane; k < cw; k += 64) {
            int p = start + k;
            if (p < MAXJ) s_jl[p] = s_jq[w][k];
        }
        if (t == 0) {
            int tot = s_c[0] + s_c[1] + s_c[2] + s_c[3];
            s_cnt = tot > MAXJ ? MAXJ : tot;
        }
    }
    __syncthreads();
    const int cnt = s_cnt;

    // stage neighbor state values for all 8 batches (all 256 threads)
    for (int x = t; x < BB * MAXJ; x += 256) {
        int k = x & (MAXJ - 1);
        if (k < cnt) s_y[x] = state[(x >> 7) * NN + s_jl[k]];
    }
    __syncthreads();

    // 32 groups x 8 lanes: group = (b,h)
    int g = t >> 3, k0 = t & 7, b = g >> 2, h = g & 3;
    const float* yb = s_y + b * MAXJ;
    float ct = ws[OFF_CTGT + h];
    float si = state[b * NN + i] * ws[OFF_CSRC + h];
    float mmax = -1e30f;
    for (int k = k0; k < cnt; k += 8) {
        float e = si + ct * yb[k]; e = e > 0.f ? e : NEG * e;
        mmax = fmaxf(mmax, e);
    }
    for (int o = 4; o; o >>= 1) mmax = fmaxf(mmax, __shfl_xor(mmax, o, 8));
    float den = 0.f, num = 0.f;
    for (int k = k0; k < cnt; k += 8) {
        float y = yb[k];
        float e = si + ct * y; e = e > 0.f ? e : NEG * e;
        float p = expf(e - mmax);
        den += p; num += p * y;
    }
    for (int o = 4; o; o >>= 1) { den += __shfl_xor(den, o, 8); num += __shfl_xor(num, o, 8); }
    if (k0 == 0) ws[OFF_SATT + i * 32 + g] = num / den;
}

// ---- se partials: block (chunk,b) sums relu(x[b,i,f]) over 64 rows ----
__global__ void k_se(float* __restrict__ ws) {
    int b = blockIdx.x & 7, chunk = blockIdx.x >> 3;
    int t = threadIdx.x; // 256
    int f = t & 63, sl = t >> 6;
    float wgw[HH];
    for (int h = 0; h < HH; ++h) wgw[h] = 0.25f * ws[OFF_WGWST + h * EE + f];
    float acc = 0.f;
    int i0 = chunk * (NN / NCHUNK);
    for (int i = i0 + sl; i < i0 + NN / NCHUNK; i += 4) {
        float v = ws[OFF_SWS + i * EE + f];
        for (int h = 0; h < HH; ++h)
            v += ws[OFF_SATT + i * 32 + b * 4 + h] * wgw[h];
        acc += fmaxf(v, 0.f);
    }
    __shared__ float red[256];
    red[t] = acc;
    __syncthreads();
    if (t < EE)
        ws[OFF_PART + (size_t)blockIdx.x * EE + t] =
            red[t] + red[t + 64] + red[t + 128] + red[t + 192];
}

// ---- S[b] = relu(se @ l1w.T + l1b) . l3w[:64] + l3b ----
__global__ void k_S(const float* __restrict__ lin1_w, const float* __restrict__ lin1_b,
                    const float* __restrict__ lin3_w, const float* __restrict__ lin3_b,
                    float* __restrict__ ws) {
    int b = blockIdx.x;
    int t = threadIdx.x; // 64
    __shared__ float s_l1T[EE * 65];
    __shared__ float s_se[EE];
    for (int it = 0; it < EE; ++it)
        s_l1T[t * 65 + it] = lin1_w[it * EE + t];
    float se = 0.f;
    for (int c = 0; c < NCHUNK; ++c)
        se += ws[OFF_PART + (size_t)(c * BB + b) * EE + t];
    s_se[t] = se;
    __syncthreads();
    float bs = lin1_b[t];
    for (int f2 = 0; f2 < EE; ++f2) bs += s_se[f2] * s_l1T[f2 * 65 + t];
    float r = fmaxf(bs, 0.f) * lin3_w[t];
    for (int o = 32; o; o >>= 1) r += __shfl_xor(r, o);
    if (t == 0) ws[OFF_S + b] = r + lin3_b[0];
}

// ---- epilogue: 4 rows/block, all 8 batches per row; l2T staged once ----
__global__ __launch_bounds__(256) void k_out2(const float* __restrict__ lin2_w,
                                              const float* __restrict__ lin2_b,
                                              const float* __restrict__ lin3_w,
                                              const float* __restrict__ ws,
                                              float* __restrict__ out) {
    __shared__ float s_l2T[EE * 65];
    __shared__ float s_wgw[HH * EE];   // 0.25-folded
    __shared__ float s_S[BB];
    __shared__ float s_l2b[EE], s_l3[EE];
    const int t = threadIdx.x;
    const int w = t >> 6, lane = t & 63;
    for (int k = t; k < EE * EE; k += 256) {
        int fp = k >> 6, f = k & 63;
        s_l2T[f * 65 + fp] = lin2_w[k];
    }
    s_wgw[t] = 0.25f * ws[OFF_WGWST + t];
    if (t < BB) s_S[t] = ws[OFF_S + t];
    if (t < EE) { s_l2b[t] = lin2_b[t]; s_l3[t] = lin3_w[EE + t]; }
    __syncthreads();

    const int i = blockIdx.x * 4 + w;
    float xsws = ws[OFF_SWS + i * EE + lane];
    float sa = (lane < 32) ? ws[OFF_SATT + i * 32 + lane] : 0.f;
    for (int b = 0; b < BB; ++b) {
        float xv = xsws;
        for (int h = 0; h < HH; ++h)
            xv += __shfl(sa, b * 4 + h) * s_wgw[h * EE + lane];
        xv = fmaxf(xv, 0.f);
        float acc = s_l2b[lane];
        for (int f = 0; f < EE; ++f) acc += __shfl(xv, f) * s_l2T[f * 65 + lane];
        float r = fmaxf(acc, 0.f) * s_l3[lane];
        for (int o = 32; o; o >>= 1) r += __shfl_xor(r, o);
        if (lane == 0) out[(size_t)b * NN + i] = s_S[b] + r;
    }
}

extern "C" void kernel_launch(void* const* d_in, const int* in_sizes, int n_in,
                              void* d_out, int out_size, void* d_ws, size_t ws_size,
                              hipStream_t stream) {
    const float* state    = (const float*)d_in[0];
    const float* strucEmb = (const float*)d_in[1];
    const int*   adj      = (const int*)d_in[2];   // int32 {0,1}, verified r11/r13
    const float* W_gat    = (const float*)d_in[3];
    const float* att      = (const float*)d_in[4];
    const float* Ws       = (const float*)d_in[5];
    const float* Wst      = (const float*)d_in[6];
    const float* lin1_w   = (const float*)d_in[7];
    const float* lin1_b   = (const float*)d_in[8];
    const float* lin2_w   = (const float*)d_in[9];
    const float* lin2_b   = (const float*)d_in[10];
    const float* lin3_w   = (const float*)d_in[11];
    const float* lin3_b   = (const float*)d_in[12];
    float* ws = (float*)d_ws;
    float* out = (float*)d_out;   // f32 output, verified r13

    k_sws  <<<dim3(NN / 16),     dim3(256), 0, stream>>>(strucEmb, Ws, W_gat, att, Wst, ws);
    k_fsatt<<<dim3(NN),          dim3(256), 0, stream>>>(adj, state, ws);
    k_se   <<<dim3(NCHUNK * BB), dim3(256), 0, stream>>>(ws);
    k_S    <<<dim3(BB),          dim3(64),  0, stream>>>(lin1_w, lin1_b, lin3_w, lin3_b, ws);
    k_out2 <<<dim3(NN / 4),      dim3(256), 0, stream>>>(lin2_w, lin2_b, lin3_w, ws, out);
}

// Round 25
// 48.137 us; speedup vs baseline: 1.7284x; 1.0032x over previous
//
#include <hip/hip_runtime.h>

#define BB 8
#define NN 2048
#define HH 4
#define EE 64
#define MAXJ 128
#define NEG 0.2f
#define NCHUNK 32

static constexpr int OFF_CSRC  = 0;                          // [4]
static constexpr int OFF_CTGT  = 4;                          // [4]
static constexpr int OFF_WGWST = 8;                          // [4][64]
static constexpr int OFF_S     = 264;                        // [8]
static constexpr int OFF_SWS   = 288;                        // [N][64]
static constexpr int OFF_SATT  = OFF_SWS + NN * EE;          // [N][32]
static constexpr int OFF_PART  = OFF_SATT + NN * 32;         // [NCHUNK*B][64]

// ---- sws: 16 rows/block, staged WsT; block 0 also does prep (cs/ct, wgw) ----
__global__ __launch_bounds__(256) void k_sws(const float* __restrict__ strucEmb,
                                             const float* __restrict__ Ws,
                                             const float* __restrict__ W_gat,
                                             const float* __restrict__ att,
                                             const float* __restrict__ Wst,
                                             float* __restrict__ ws) {
    __shared__ float s_wsT[EE * 65];   // s_wsT[e*65+f] = Ws[f][e]
    __shared__ float s_emb[16 * EE];
    const int t = threadIdx.x;
    const int w = t >> 6, lane = t & 63;
    const int i0 = blockIdx.x * 16;
    for (int k = t; k < EE * EE; k += 256)
        s_wsT[(k & 63) * 65 + (k >> 6)] = Ws[k];       // coalesced read
    for (int k = t; k < 16 * EE; k += 256)
        s_emb[k] = strucEmb[(size_t)i0 * EE + k];
    __syncthreads();
    for (int q = 0; q < 4; ++q) {
        int r = w * 4 + q;
        float v = s_emb[r * EE + lane];
        float acc = 0.f;
        for (int e = 0; e < EE; ++e)
            acc += __shfl(v, e) * s_wsT[e * 65 + lane];
        ws[OFF_SWS + (size_t)(i0 + r) * EE + lane] = acc;
    }
    if (blockIdx.x == 0) {
        int h = t >> 6, f = t & 63;
        float acc = 0.f;
        for (int e = 0; e < EE; ++e) acc += W_gat[h * EE + e] * Wst[f * EE + e];
        ws[OFF_WGWST + t] = acc;
        if (t < 2 * HH) {
            int hh = t & 3;
            const float* wgx = W_gat + hh * EE;
            const float* av  = att + hh * 2 * EE + (t >= HH ? EE : 0);
            float a2 = 0.f;
            for (int e = 0; e < EE; ++e) a2 += wgx[e] * av[e];
            if (t < HH) ws[OFF_CSRC + hh] = a2; else ws[OFF_CTGT + hh] = a2;
        }
    }
}

// ---- fsatt: vectorized 4-wave scan + gather + sparse softmax ----
__global__ __launch_bounds__(256) void k_fsatt(const int* __restrict__ adj,
                                               const float* __restrict__ state,
                                               float* __restrict__ ws) {
    __shared__ int   s_jq[4][MAXJ];
    __shared__ int   s_c[4];
    __shared__ int   s_jl[MAXJ];
    __shared__ int   s_cnt;
    __shared__ float s_y[BB * MAXJ];
    const int i = blockIdx.x;
    const int t = threadIdx.x;
    const int w = t >> 6, lane = t & 63;

    {
        const int4* a4 = (const int4*)(adj + (size_t)i * NN) + w * 128;
        int base = 0;
        const unsigned long long below = (1ull << lane) - 1ull;
        for (int q = 0; q < 2; ++q) {
            int4 v = a4[q * 64 + lane];
            int j0 = w * 512 + (q * 64 + lane) * 4;
            int eb = (v.x == 0 ? 1 : 0) | (v.y == 0 ? 2 : 0) |
                     (v.z == 0 ? 4 : 0) | (v.w == 0 ? 8 : 0);
            unsigned long long b0 = __ballot(eb & 1), b1 = __ballot(eb & 2);
            unsigned long long b2 = __ballot(eb & 4), b3 = __ballot(eb & 8);
            int pos = base + __popcll(b0 & below) + __popcll(b1 & below)
                           + __popcll(b2 & below) + __popcll(b3 & below);
            if (eb & 1) { if (pos < MAXJ) s_jq[w][pos] = j0 + 0; ++pos; }
            if (eb & 2) { if (pos < MAXJ) s_jq[w][pos] = j0 + 1; ++pos; }
            if (eb & 4) { if (pos < MAXJ) s_jq[w][pos] = j0 + 2; ++pos; }
            if (eb & 8) { if (pos < MAXJ) s_jq[w][pos] = j0 + 3; ++pos; }
            base += __popcll(b0) + __popcll(b1) + __popcll(b2) + __popcll(b3);
        }
        if (lane == 0) s_c[w] = base > MAXJ ? MAXJ : base;
    }
    __syncthreads();
    {
        int start = 0;
        for (int q = 0; q < w; ++q) start += s_c[q];
        int cw = s_c[w];
        for (int k = lane; k < cw; k += 64) {
            int p = start + k;
            if (p < MAXJ) s_jl[p] = s_jq[w][k];
        }
        if (t == 0) {
            int tot = s_c[0] + s_c[1] + s_c[2] + s_c[3];
            s_cnt = tot > MAXJ ? MAXJ : tot;
        }
    }
    __syncthreads();
    const int cnt = s_cnt;

    for (int x = t; x < BB * MAXJ; x += 256) {
        int k = x & (MAXJ - 1);
        if (k < cnt) s_y[x] = state[(x >> 7) * NN + s_jl[k]];
    }
    __syncthreads();

    int g = t >> 3, k0 = t & 7, b = g >> 2, h = g & 3;
    const float* yb = s_y + b * MAXJ;
    float ct = ws[OFF_CTGT + h];
    float si = state[b * NN + i] * ws[OFF_CSRC + h];
    float mmax = -1e30f;
    for (int k = k0; k < cnt; k += 8) {
        float e = si + ct * yb[k]; e = e > 0.f ? e : NEG * e;
        mmax = fmaxf(mmax, e);
    }
    for (int o = 4; o; o >>= 1) mmax = fmaxf(mmax, __shfl_xor(mmax, o, 8));
    float den = 0.f, num = 0.f;
    for (int k = k0; k < cnt; k += 8) {
        float y = yb[k];
        float e = si + ct * y; e = e > 0.f ? e : NEG * e;
        float p = expf(e - mmax);
        den += p; num += p * y;
    }
    for (int o = 4; o; o >>= 1) { den += __shfl_xor(den, o, 8); num += __shfl_xor(num, o, 8); }
    if (k0 == 0) ws[OFF_SATT + i * 32 + g] = num / den;
}

// ---- se partials: block (chunk,b) sums relu(x[b,i,f]) over 64 rows ----
__global__ void k_se(float* __restrict__ ws) {
    int b = blockIdx.x & 7, chunk = blockIdx.x >> 3;
    int t = threadIdx.x; // 256
    int f = t & 63, sl = t >> 6;
    float wgw[HH];
    for (int h = 0; h < HH; ++h) wgw[h] = 0.25f * ws[OFF_WGWST + h * EE + f];
    float acc = 0.f;
    int i0 = chunk * (NN / NCHUNK);
    for (int i = i0 + sl; i < i0 + NN / NCHUNK; i += 4) {
        float v = ws[OFF_SWS + i * EE + f];
        for (int h = 0; h < HH; ++h)
            v += ws[OFF_SATT + i * 32 + b * 4 + h] * wgw[h];
        acc += fmaxf(v, 0.f);
    }
    __shared__ float red[256];
    red[t] = acc;
    __syncthreads();
    if (t < EE)
        ws[OFF_PART + (size_t)blockIdx.x * EE + t] =
            red[t] + red[t + 64] + red[t + 128] + red[t + 192];
}

// ---- S[b] = relu(se @ l1w.T + l1b) . l3w[:64] + l3b ----
__global__ void k_S(const float* __restrict__ lin1_w, const float* __restrict__ lin1_b,
                    const float* __restrict__ lin3_w, const float* __restrict__ lin3_b,
                    float* __restrict__ ws) {
    int b = blockIdx.x;
    int t = threadIdx.x; // 64
    __shared__ float s_l1T[EE * 65];
    __shared__ float s_se[EE];
    for (int it = 0; it < EE; ++it)
        s_l1T[t * 65 + it] = lin1_w[it * EE + t];
    float se = 0.f;
    for (int c = 0; c < NCHUNK; ++c)
        se += ws[OFF_PART + (size_t)(c * BB + b) * EE + t];
    s_se[t] = se;
    __syncthreads();
    float bs = lin1_b[t];
    for (int f2 = 0; f2 < EE; ++f2) bs += s_se[f2] * s_l1T[f2 * 65 + t];
    float r = fmaxf(bs, 0.f) * lin3_w[t];
    for (int o = 32; o; o >>= 1) r += __shfl_xor(r, o);
    if (t == 0) ws[OFF_S + b] = r + lin3_b[0];
}

// ---- epilogue: 1 row/wave, lin2 row in REGISTERS; matvec = readlane+FMA ----
__global__ __launch_bounds__(256) void k_out3(const float* __restrict__ lin2_w,
                                              const float* __restrict__ lin2_b,
                                              const float* __restrict__ lin3_w,
                                              const float* __restrict__ ws,
                                              float* __restrict__ out) {
    __shared__ float s_l2T[EE * 65];
    __shared__ float s_wgw[HH * EE];   // 0.25-folded
    __shared__ float s_S[BB];
    __shared__ float s_l2b[EE], s_l3[EE];
    const int t = threadIdx.x;
    const int w = t >> 6, lane = t & 63;
    for (int k = t; k < EE * EE; k += 256) {
        int fp = k >> 6, f = k & 63;
        s_l2T[f * 65 + fp] = lin2_w[k];    // coalesced global read
    }
    s_wgw[t] = 0.25f * ws[OFF_WGWST + t];
    if (t < BB) s_S[t] = ws[OFF_S + t];
    if (t < EE) { s_l2b[t] = lin2_b[t]; s_l3[t] = lin3_w[EE + t]; }
    __syncthreads();

    // lane caches row 'lane' of lin2_w in registers (64 conflict-free LDS reads)
    float lr[EE];
    #pragma unroll
    for (int f = 0; f < EE; ++f) lr[f] = s_l2T[f * 65 + lane];

    const int i = blockIdx.x * 4 + w;   // 512 blocks x 4 waves = 2048 rows
    float xsws = ws[OFF_SWS + (size_t)i * EE + lane];
    float sa = (lane < 32) ? ws[OFF_SATT + i * 32 + lane] : 0.f;
    for (int b = 0; b < BB; ++b) {
        float xv = xsws;
        for (int h = 0; h < HH; ++h)
            xv += __shfl(sa, b * 4 + h) * s_wgw[h * EE + lane];
        xv = fmaxf(xv, 0.f);
        float acc = s_l2b[lane];
        #pragma unroll
        for (int f = 0; f < EE; ++f) acc += __shfl(xv, f) * lr[f];
        float r = fmaxf(acc, 0.f) * s_l3[lane];
        for (int o = 32; o; o >>= 1) r += __shfl_xor(r, o);
        if (lane == 0) out[(size_t)b * NN + i] = s_S[b] + r;
    }
}

extern "C" void kernel_launch(void* const* d_in, const int* in_sizes, int n_in,
                              void* d_out, int out_size, void* d_ws, size_t ws_size,
                              hipStream_t stream) {
    const float* state    = (const float*)d_in[0];
    const float* strucEmb = (const float*)d_in[1];
    const int*   adj      = (const int*)d_in[2];   // int32 {0,1}, verified r11/r13
    const float* W_gat    = (const float*)d_in[3];
    const float* att      = (const float*)d_in[4];
    const float* Ws       = (const float*)d_in[5];
    const float* Wst      = (const float*)d_in[6];
    const float* lin1_w   = (const float*)d_in[7];
    const float* lin1_b   = (const float*)d_in[8];
    const float* lin2_w   = (const float*)d_in[9];
    const float* lin2_b   = (const float*)d_in[10];
    const float* lin3_w   = (const float*)d_in[11];
    const float* lin3_b   = (const float*)d_in[12];
    float* ws = (float*)d_ws;
    float* out = (float*)d_out;   // f32 output, verified r13

    k_sws  <<<dim3(NN / 16),     dim3(256), 0, stream>>>(strucEmb, Ws, W_gat, att, Wst, ws);
    k_fsatt<<<dim3(NN),          dim3(256), 0, stream>>>(adj, state, ws);
    k_se   <<<dim3(NCHUNK * BB), dim3(256), 0, stream>>>(ws);
    k_S    <<<dim3(BB),          dim3(64),  0, stream>>>(lin1_w, lin1_b, lin3_w, lin3_b, ws);
    k_out3 <<<dim3(NN / 4),      dim3(256), 0, stream>>>(lin2_w, lin2_b, lin3_w, ws, out);
}